// Round 2
// baseline (116.577 us; speedup 1.0000x reference)
//
#include <hip/hip_runtime.h>
#include <math.h>

constexpr int NATOMS = 1024;          // atoms per sample
// layout of staged sums per sample (16 floats in d_ws):
//  [0..2]  sum x_i      [3..5] sum y_i
//  [6..14] sum x_i*y_j (row-major i*3+j)
//  [15]    sum |x|^2 + |y|^2

__device__ __forceinline__ float wred(float v) {
#pragma unroll
    for (int o = 32; o > 0; o >>= 1) v += __shfl_xor(v, o, 64);
    return v;
}

// ---------------- Kernel A: memory-bound reduction, one wave per sample ----------------
__global__ __launch_bounds__(256) void rmsd_reduce(
    const float* __restrict__ inp, const float* __restrict__ tgt,
    const int* __restrict__ natoms, float* __restrict__ ws, int batch)
{
    const int wave = threadIdx.x >> 6;
    const int lane = threadIdx.x & 63;
    const int b = blockIdx.x * 4 + wave;
    if (b >= batch) return;
    const int n = natoms[b];

    const float4* __restrict__ x0 = (const float4*)(inp + (size_t)b * (3 * NATOMS));
    const float4* __restrict__ y0 = (const float4*)(tgt + (size_t)b * (3 * NATOMS));

    float acc[16];
#pragma unroll
    for (int i = 0; i < 16; ++i) acc[i] = 0.f;

    // 4 chunks of 256 atoms.
    //  - chunk skipped entirely when cbase >= n (wave-uniform: one sample per wave)
    //  - inside the boundary chunk, lanes whose 4-atom group starts past n issue
    //    no loads at all (exec-masked VMEM -> no HBM traffic for dead lanes)
#pragma unroll
    for (int c = 0; c < 4; ++c) {
        const int cbase = c * 256;
        if (cbase < n) {
            const int abase = cbase + lane * 4;
            if (abase < n) {
                const float4* x4 = x0 + c * 192 + lane * 3;   // 4 atoms = 12 floats = 3 float4
                const float4* y4 = y0 + c * 192 + lane * 3;
                float4 xa = x4[0], xb = x4[1], xc = x4[2];
                float4 ya = y4[0], yb = y4[1], yc = y4[2];
                const float X[4][3] = {{xa.x,xa.y,xa.z},{xa.w,xb.x,xb.y},{xb.z,xb.w,xc.x},{xc.y,xc.z,xc.w}};
                const float Y[4][3] = {{ya.x,ya.y,ya.z},{ya.w,yb.x,yb.y},{yb.z,yb.w,yc.x},{yc.y,yc.z,yc.w}};
#pragma unroll
                for (int j = 0; j < 4; ++j) {
                    const float m = (abase + j < n) ? 1.f : 0.f;
                    const float p0 = X[j][0]*m, p1 = X[j][1]*m, p2 = X[j][2]*m;
                    const float q0 = Y[j][0]*m, q1 = Y[j][1]*m, q2 = Y[j][2]*m;
                    acc[0] += p0; acc[1] += p1; acc[2] += p2;
                    acc[3] += q0; acc[4] += q1; acc[5] += q2;
                    acc[6]  += p0*q0; acc[7]  += p0*q1; acc[8]  += p0*q2;
                    acc[9]  += p1*q0; acc[10] += p1*q1; acc[11] += p1*q2;
                    acc[12] += p2*q0; acc[13] += p2*q1; acc[14] += p2*q2;
                    acc[15] += p0*p0 + p1*p1 + p2*p2 + q0*q0 + q1*q1 + q2*q2;
                }
            }
        }
    }

#pragma unroll
    for (int i = 0; i < 16; ++i) acc[i] = wred(acc[i]);

    if (lane == 0) {
        float4* o = (float4*)(ws + (size_t)b * 16);
        o[0] = make_float4(acc[0],  acc[1],  acc[2],  acc[3]);
        o[1] = make_float4(acc[4],  acc[5],  acc[6],  acc[7]);
        o[2] = make_float4(acc[8],  acc[9],  acc[10], acc[11]);
        o[3] = make_float4(acc[12], acc[13], acc[14], acc[15]);
    }
}

// ---------------- Kernel B: f64 Kabsch solve, one thread per sample ----------------
__global__ __launch_bounds__(256) void rmsd_solve(
    const float* __restrict__ ws, const int* __restrict__ natoms,
    float* __restrict__ out, int batch)
{
    const int b = blockIdx.x * 256 + threadIdx.x;
    if (b >= batch) return;
    const int n = natoms[b];

    const float4* s4 = (const float4*)(ws + (size_t)b * 16);
    const float4 v0 = s4[0], v1 = s4[1], v2 = s4[2], v3 = s4[3];
    const double sx0 = v0.x, sx1 = v0.y, sx2 = v0.z;
    const double sy0 = v0.w, sy1 = v1.x, sy2 = v1.y;
    const double c00 = v1.z, c01 = v1.w, c02 = v2.x;
    const double c10 = v2.y, c11 = v2.z, c12 = v2.w;
    const double c20 = v3.x, c21 = v3.y, c22 = v3.z;
    const double sq  = v3.w;

    const double nd = (double)n;
    const double inv = 1.0 / nd;

    // centered covariance R[i][j] = sum x_i y_j - (sum x_i)(sum y_j)/n
    double R[3][3];
    R[0][0] = c00 - sx0*sy0*inv; R[0][1] = c01 - sx0*sy1*inv; R[0][2] = c02 - sx0*sy2*inv;
    R[1][0] = c10 - sx1*sy0*inv; R[1][1] = c11 - sx1*sy1*inv; R[1][2] = c12 - sx1*sy2*inv;
    R[2][0] = c20 - sx2*sy0*inv; R[2][1] = c21 - sx2*sy1*inv; R[2][2] = c22 - sx2*sy2*inv;
    const double exy = sq - (sx0*sx0 + sx1*sx1 + sx2*sx2 + sy0*sy0 + sy1*sy1 + sy2*sy2) * inv;

    const double detR =
          R[0][0]*(R[1][1]*R[2][2] - R[1][2]*R[2][1])
        - R[0][1]*(R[1][0]*R[2][2] - R[1][2]*R[2][0])
        + R[0][2]*(R[1][0]*R[2][1] - R[1][1]*R[2][0]);

    // K = R^T R (symmetric PSD); eigenvalues are squared singular values
    double K00=0, K01=0, K02=0, K11=0, K12=0, K22=0;
    for (int k = 0; k < 3; ++k) {
        K00 += R[k][0]*R[k][0]; K01 += R[k][0]*R[k][1]; K02 += R[k][0]*R[k][2];
        K11 += R[k][1]*R[k][1]; K12 += R[k][1]*R[k][2]; K22 += R[k][2]*R[k][2];
    }

    // analytic symmetric 3x3 eigenvalues (trig method), f64
    const double qm = (K00 + K11 + K22) / 3.0;
    const double p1 = K01*K01 + K02*K02 + K12*K12;
    const double p2 = (K00-qm)*(K00-qm) + (K11-qm)*(K11-qm) + (K22-qm)*(K22-qm) + 2.0*p1;
    double e1, e2, e3;
    if (p2 <= 1e-30) {
        e1 = e2 = e3 = qm;
    } else {
        const double p = sqrt(p2 / 6.0);
        const double pinv = 1.0 / p;
        const double B00 = (K00-qm)*pinv, B11 = (K11-qm)*pinv, B22 = (K22-qm)*pinv;
        const double B01 = K01*pinv, B02 = K02*pinv, B12 = K12*pinv;
        const double detB =
              B00*(B11*B22 - B12*B12)
            - B01*(B01*B22 - B12*B02)
            + B02*(B01*B12 - B11*B02);
        double r = detB * 0.5;
        r = fmin(1.0, fmax(-1.0, r));
        const double phi = acos(r) / 3.0;
        e1 = qm + 2.0*p*cos(phi);
        e3 = qm + 2.0*p*cos(phi + 2.0943951023931953);  // +2*pi/3 -> smallest
        e2 = 3.0*qm - e1 - e3;
    }
    const double S1 = sqrt(fmax(e1, 0.0));
    const double S2 = sqrt(fmax(e2, 0.0));
    const double S3 = sqrt(fmax(e3, 0.0));
    const double dsg = (detR < 0.0) ? -1.0 : 1.0;  // detR==0 => S3==0, sign moot
    const double sv = S1 + S2 + dsg * S3;

    const double e = exy - 2.0 * sv;
    out[b] = (float)sqrt(fmax(e * inv, 1e-12));
}

extern "C" void kernel_launch(void* const* d_in, const int* in_sizes, int n_in,
                              void* d_out, int out_size, void* d_ws, size_t ws_size,
                              hipStream_t stream) {
    const float* inp = (const float*)d_in[0];
    const float* tgt = (const float*)d_in[1];
    const int*   na  = (const int*)d_in[2];
    float* out = (float*)d_out;
    float* ws  = (float*)d_ws;   // needs batch*16 floats = 256 KB
    const int batch = in_sizes[2];  // 4096

    rmsd_reduce<<<(batch + 3) / 4, 256, 0, stream>>>(inp, tgt, na, ws, batch);
    rmsd_solve<<<(batch + 255) / 256, 256, 0, stream>>>(ws, na, out, batch);
}

// Round 3
// 115.424 us; speedup vs baseline: 1.0100x; 1.0100x over previous
//
#include <hip/hip_runtime.h>
#include <math.h>

constexpr int NATOMS = 1024;   // atoms per sample

// One wave per sample. Fused: masked accumulate -> reduce-scatter (17 shfls)
// -> broadcast-gather (16 shfls) -> wave-uniform f64 Kabsch solve -> lane 0 store.
__global__ __launch_bounds__(256) void rmsd_fused(
    const float* __restrict__ inp, const float* __restrict__ tgt,
    const int* __restrict__ natoms, float* __restrict__ out, int batch)
{
    const int wave = threadIdx.x >> 6;
    const int lane = threadIdx.x & 63;
    const int b = blockIdx.x * 4 + wave;
    if (b >= batch) return;
    const int n = natoms[b];   // wave-uniform (one sample per wave)

    const float4* __restrict__ x0 = (const float4*)(inp + (size_t)b * (3 * NATOMS));
    const float4* __restrict__ y0 = (const float4*)(tgt + (size_t)b * (3 * NATOMS));

    // acc: 0-2 sum x, 3-5 sum y, 6-14 sum x_i*y_j (i*3+j), 15 sum |x|^2+|y|^2
    float acc[16];
#pragma unroll
    for (int i = 0; i < 16; ++i) acc[i] = 0.f;

    // 4 chunks of 256 atoms; whole chunk skipped (wave-uniform) when past n,
    // per-lane load skip in the boundary chunk (exec-masked VMEM = no traffic).
#pragma unroll
    for (int c = 0; c < 4; ++c) {
        const int cbase = c * 256;
        if (cbase < n) {
            const int abase = cbase + (lane << 2);
            if (abase < n) {
                const float4* x4 = x0 + c * 192 + lane * 3;   // 4 atoms = 3 float4
                const float4* y4 = y0 + c * 192 + lane * 3;
                float4 xa = x4[0], xb = x4[1], xc = x4[2];
                float4 ya = y4[0], yb = y4[1], yc = y4[2];
                const float X[4][3] = {{xa.x,xa.y,xa.z},{xa.w,xb.x,xb.y},{xb.z,xb.w,xc.x},{xc.y,xc.z,xc.w}};
                const float Y[4][3] = {{ya.x,ya.y,ya.z},{ya.w,yb.x,yb.y},{yb.z,yb.w,yc.x},{yc.y,yc.z,yc.w}};
#pragma unroll
                for (int j = 0; j < 4; ++j) {
                    const float m = (abase + j < n) ? 1.f : 0.f;
                    const float p0 = X[j][0]*m, p1 = X[j][1]*m, p2 = X[j][2]*m;
                    const float q0 = Y[j][0]*m, q1 = Y[j][1]*m, q2 = Y[j][2]*m;
                    acc[0] += p0; acc[1] += p1; acc[2] += p2;
                    acc[3] += q0; acc[4] += q1; acc[5] += q2;
                    acc[6]  += p0*q0; acc[7]  += p0*q1; acc[8]  += p0*q2;
                    acc[9]  += p1*q0; acc[10] += p1*q1; acc[11] += p1*q2;
                    acc[12] += p2*q0; acc[13] += p2*q1; acc[14] += p2*q2;
                    acc[15] += p0*p0 + p1*p1 + p2*p2 + q0*q0 + q1*q1 + q2*q2;
                }
            }
        }
    }

    // ---- reduce-scatter within 16-lane groups: offsets 1,2,4,8 (15 shfls) ----
    // After step k, each lane keeps the half of its live set selected by its
    // lane bit k; final: lane L holds group-sum of acc[bitrev4(L&15)].
#pragma unroll
    for (int k = 0; k < 4; ++k) {
        const int half = 8 >> k;              // 8,4,2,1 live pairs
        const bool hi = (lane >> k) & 1;
#pragma unroll
        for (int j = 0; j < 8; ++j) {
            if (j < half) {
                const float a  = acc[j], bb = acc[j + half];
                const float send = hi ? a : bb;     // send what partner keeps
                const float recv = __shfl_xor(send, 1 << k, 64);
                acc[j] = (hi ? bb : a) + recv;
            }
        }
    }
    float v = acc[0];
    v += __shfl_xor(v, 16, 64);
    v += __shfl_xor(v, 32, 64);
    // lane L now holds the full-wave sum of acc[bitrev4(L&15)]

    // ---- broadcast-gather: every lane collects all 16 sums (16 shfls) ----
    // sum j lives in lane bitrev4(j)
    float s[16];
    {
        constexpr int rev[16] = {0,8,4,12,2,10,6,14,1,9,5,13,3,11,7,15};
#pragma unroll
        for (int j = 0; j < 16; ++j) s[j] = __shfl(v, rev[j], 64);
    }

    // ---- wave-uniform f64 Kabsch solve (identical work on all 64 lanes) ----
    const double sx0 = s[0], sx1 = s[1], sx2 = s[2];
    const double sy0 = s[3], sy1 = s[4], sy2 = s[5];
    const double nd  = (double)n;
    const double inv = 1.0 / nd;

    double R[3][3];
    R[0][0] = s[6]  - sx0*sy0*inv; R[0][1] = s[7]  - sx0*sy1*inv; R[0][2] = s[8]  - sx0*sy2*inv;
    R[1][0] = s[9]  - sx1*sy0*inv; R[1][1] = s[10] - sx1*sy1*inv; R[1][2] = s[11] - sx1*sy2*inv;
    R[2][0] = s[12] - sx2*sy0*inv; R[2][1] = s[13] - sx2*sy1*inv; R[2][2] = s[14] - sx2*sy2*inv;
    const double exy = (double)s[15]
        - (sx0*sx0 + sx1*sx1 + sx2*sx2 + sy0*sy0 + sy1*sy1 + sy2*sy2) * inv;

    const double detR =
          R[0][0]*(R[1][1]*R[2][2] - R[1][2]*R[2][1])
        - R[0][1]*(R[1][0]*R[2][2] - R[1][2]*R[2][0])
        + R[0][2]*(R[1][0]*R[2][1] - R[1][1]*R[2][0]);

    // K = R^T R (symmetric PSD); eigenvalues are squared singular values
    double K00=0, K01=0, K02=0, K11=0, K12=0, K22=0;
#pragma unroll
    for (int k = 0; k < 3; ++k) {
        K00 += R[k][0]*R[k][0]; K01 += R[k][0]*R[k][1]; K02 += R[k][0]*R[k][2];
        K11 += R[k][1]*R[k][1]; K12 += R[k][1]*R[k][2]; K22 += R[k][2]*R[k][2];
    }

    // analytic symmetric 3x3 eigenvalues (trig method), f64
    const double qm = (K00 + K11 + K22) / 3.0;
    const double p1 = K01*K01 + K02*K02 + K12*K12;
    const double p2 = (K00-qm)*(K00-qm) + (K11-qm)*(K11-qm) + (K22-qm)*(K22-qm) + 2.0*p1;
    double e1, e2, e3;
    if (p2 <= 1e-30) {
        e1 = e2 = e3 = qm;
    } else {
        const double p = sqrt(p2 / 6.0);
        const double pinv = 1.0 / p;
        const double B00 = (K00-qm)*pinv, B11 = (K11-qm)*pinv, B22 = (K22-qm)*pinv;
        const double B01 = K01*pinv, B02 = K02*pinv, B12 = K12*pinv;
        const double detB =
              B00*(B11*B22 - B12*B12)
            - B01*(B01*B22 - B12*B02)
            + B02*(B01*B12 - B11*B02);
        double r = detB * 0.5;
        r = fmin(1.0, fmax(-1.0, r));
        const double phi = acos(r) / 3.0;
        e1 = qm + 2.0*p*cos(phi);
        e3 = qm + 2.0*p*cos(phi + 2.0943951023931953);  // +2*pi/3 -> smallest
        e2 = 3.0*qm - e1 - e3;
    }
    const double S1 = sqrt(fmax(e1, 0.0));
    const double S2 = sqrt(fmax(e2, 0.0));
    const double S3 = sqrt(fmax(e3, 0.0));
    const double dsg = (detR < 0.0) ? -1.0 : 1.0;  // detR==0 => S3==0, sign moot
    const double sv = S1 + S2 + dsg * S3;

    const double e = exy - 2.0 * sv;
    if (lane == 0) out[b] = (float)sqrt(fmax(e * inv, 1e-12));
}

extern "C" void kernel_launch(void* const* d_in, const int* in_sizes, int n_in,
                              void* d_out, int out_size, void* d_ws, size_t ws_size,
                              hipStream_t stream) {
    const float* inp = (const float*)d_in[0];
    const float* tgt = (const float*)d_in[1];
    const int*   na  = (const int*)d_in[2];
    float* out = (float*)d_out;
    const int batch = in_sizes[2];  // 4096

    rmsd_fused<<<(batch + 3) / 4, 256, 0, stream>>>(inp, tgt, na, out, batch);
}